// Round 5
// baseline (321.647 us; speedup 1.0000x reference)
//
#include <hip/hip_runtime.h>
#include <math.h>

// Problem constants
#define BB    64
#define TT    512
#define TWOH  1024
#define NP_STRIDE ((TT + 1) * TWOH)  // 513*1024
#define TPB   64                 // t-rows per k_ct block
#define NG    (TT / TPB)         // 8 ct-partials per b

// native clang vector type (vectorized loads/stores)
typedef float vfloat4 __attribute__((ext_vector_type(4)));

// NOTE (R3 post-mortem): __builtin_nontemporal_store on out_np caused
// post-timing divergence under the harness's re-poison path — no nt stores.
// NOTE (R1-R4 post-mortem): the fused read+compute+big-write kernel pins at
// ~2.7 TB/s across 5 structural variants (register staging, straight-line,
// LDS-DMA, 2x occupancy) while pure fill/copy patterns run 6.3-6.5 TB/s on
// the same chip. Also: the harness's two ~514MB re-poison fills (~166 us)
// are inside the timed region; only ~100 us is controllable.
// This version splits into PURE patterns only:
//   qgemm (small GEMM) | copy (stream, m13-proven 6.3 TB/s) |
//   scores (read-only stream) | ct (softmax + GEMV, read-only stream) |
//   ctcomb (tiny). Diagnostic: if k_copy also runs ~2.7 TB/s, the wall is
//   global (chip state), not kernel structure.

// -------------------------------------------------------------------------
// K1: q[b][e] = sum_d h[b,d] * W[d,e]  (full-K, single kernel)
// grid = (4 e-chunks, 64 b) = 256 blocks, 256 threads.
// -------------------------------------------------------------------------
__global__ __launch_bounds__(256) void k_qgemm(const float* __restrict__ h,
                                               const float* __restrict__ W,
                                               float* __restrict__ q) {
    const int tid = threadIdx.x;
    const int e   = blockIdx.x * 256 + tid;      // 0..1023
    const int b   = blockIdx.y;                  // 0..63

    __shared__ float sh[TWOH];
    ((vfloat4*)sh)[tid] = ((const vfloat4*)(h + (size_t)b * TWOH))[tid];
    __syncthreads();

    const float* __restrict__ Wp = W + e;
    float acc = 0.f;
    #pragma unroll 16
    for (int d = 0; d < TWOH; ++d)
        acc = fmaf(sh[d], Wp[(size_t)d * TWOH], acc);

    q[(size_t)b * TWOH + e] = acc;
}

// -------------------------------------------------------------------------
// K2: pure stream copy prev -> new_prev rows [0,512) (+1-row/b dst shift),
// plus tail blocks writing new_prev[b,512,:] = h[b,:].
// Main: 8192 blocks x 256 thr x 4 float4 (16 KB/block contiguous).
// dst4 = i4 + (b<<8) since dst = b*513*256 + rem, b = i4>>17.
// Tail: 64 blocks x 256 thr x 1 float4.
// -------------------------------------------------------------------------
__global__ __launch_bounds__(256) void k_copy(const float* __restrict__ prev,
                                              const float* __restrict__ h,
                                              float* __restrict__ out_np) {
    const int gx  = blockIdx.x;
    const int tid = threadIdx.x;
    const vfloat4* __restrict__ in4 = (const vfloat4*)prev;
    vfloat4* __restrict__ out4      = (vfloat4*)out_np;

    if (gx < 8192) {
        const int base = gx * 1024 + tid;        // f4 index, 4 chunks of 256
        vfloat4 v0 = in4[base];
        vfloat4 v1 = in4[base + 256];
        vfloat4 v2 = in4[base + 512];
        vfloat4 v3 = in4[base + 768];
        const int i0 = base,       b0 = i0 >> 17;
        const int i1 = base + 256, b1 = i1 >> 17;
        const int i2 = base + 512, b2 = i2 >> 17;
        const int i3 = base + 768, b3 = i3 >> 17;
        out4[i0 + (b0 << 8)] = v0;
        out4[i1 + (b1 << 8)] = v1;
        out4[i2 + (b2 << 8)] = v2;
        out4[i3 + (b3 << 8)] = v3;
    } else {
        // concat row: new_prev[b, 512, :] = h[b, :]
        const int flat = (gx - 8192) * 256 + tid;    // 0..16383
        const int b    = flat >> 8;
        const int e4   = flat & 255;
        out4[(size_t)b * (513 * 256) + 512 * 256 + e4] =
            ((const vfloat4*)h)[flat];
    }
}

// -------------------------------------------------------------------------
// K3: raw scores, read-only stream. Each wave owns one t-row:
// 4 float4 loads -> dot with q -> butterfly -> lane0 scalar store.
// No LDS, no barriers. grid = (128, 64) = 8192 blocks.
// -------------------------------------------------------------------------
__global__ __launch_bounds__(256, 8) void k_scores(const float* __restrict__ prev,
                                                   const float* __restrict__ q,
                                                   float* __restrict__ s) {
    const int tid  = threadIdx.x;
    const int lane = tid & 63;
    const int wid  = tid >> 6;
    const int b    = blockIdx.y;
    const int t    = blockIdx.x * 4 + wid;       // 0..511

    const vfloat4* __restrict__ pr =
        (const vfloat4*)(prev + ((size_t)b * TT + t) * TWOH) + lane;
    const vfloat4* __restrict__ qv =
        (const vfloat4*)(q + (size_t)b * TWOH) + lane;

    const vfloat4 v0 = pr[0],   v1 = pr[64],  v2 = pr[128], v3 = pr[192];
    const vfloat4 q0 = qv[0],   q1 = qv[64],  q2 = qv[128], q3 = qv[192];

    float d0 = v0.x * q0.x; d0 = fmaf(v0.y, q0.y, d0);
    d0 = fmaf(v0.z, q0.z, d0); d0 = fmaf(v0.w, q0.w, d0);
    float d1 = v1.x * q1.x; d1 = fmaf(v1.y, q1.y, d1);
    d1 = fmaf(v1.z, q1.z, d1); d1 = fmaf(v1.w, q1.w, d1);
    float d2 = v2.x * q2.x; d2 = fmaf(v2.y, q2.y, d2);
    d2 = fmaf(v2.z, q2.z, d2); d2 = fmaf(v2.w, q2.w, d2);
    float d3 = v3.x * q3.x; d3 = fmaf(v3.y, q3.y, d3);
    d3 = fmaf(v3.z, q3.z, d3); d3 = fmaf(v3.w, q3.w, d3);
    float pd = (d0 + d1) + (d2 + d3);
    #pragma unroll
    for (int off = 32; off > 0; off >>= 1)
        pd += __shfl_xor(pd, off, 64);

    if (lane == 0) s[b * TT + t] = pd;
}

// -------------------------------------------------------------------------
// K4: exact softmax over the full 512 scores (block reduce) + GEMV partial
// over this block's 64 t-rows. Read-only stream of prev (L3-warm).
// grid = (NG=8, 64) = 512 blocks = 2/CU; thread owns float4 at e=4*tid.
// -------------------------------------------------------------------------
__global__ __launch_bounds__(256) void k_ct(const float* __restrict__ prev,
                                            const float* __restrict__ s,
                                            float* __restrict__ ctp) {
    const int tid  = threadIdx.x;
    const int lane = tid & 63;
    const int wid  = tid >> 6;
    const int g    = blockIdx.x;                 // t-group 0..7
    const int b    = blockIdx.y;

    __shared__ float ss[TT];
    __shared__ float als[TT];
    __shared__ float red[8];

    // stage all 512 scores (threads 0..127 load one float4 each)
    if (tid < 128)
        ((vfloat4*)ss)[tid] = ((const vfloat4*)(s + b * TT))[tid];
    __syncthreads();

    const float v0 = ss[tid];
    const float v1 = ss[tid + 256];

    // block max
    float m2 = fmaxf(v0, v1);
    #pragma unroll
    for (int off = 32; off > 0; off >>= 1)
        m2 = fmaxf(m2, __shfl_xor(m2, off, 64));
    if (lane == 0) red[wid] = m2;
    __syncthreads();
    const float M = fmaxf(fmaxf(red[0], red[1]), fmaxf(red[2], red[3]));

    // block sum of exp
    const float e0 = __expf(v0 - M);
    const float e1 = __expf(v1 - M);
    float l2 = e0 + e1;
    #pragma unroll
    for (int off = 32; off > 0; off >>= 1)
        l2 += __shfl_xor(l2, off, 64);
    if (lane == 0) red[4 + wid] = l2;
    __syncthreads();
    const float L   = (red[4] + red[5]) + (red[6] + red[7]);
    const float inv = 1.0f / L;

    als[tid]       = e0 * inv;
    als[tid + 256] = e1 * inv;
    __syncthreads();

    // GEMV partial over this block's 64 rows; thread owns float4 index tid
    const vfloat4* __restrict__ pr =
        (const vfloat4*)(prev + ((size_t)b * TT + g * TPB) * TWOH) + tid;
    vfloat4 acc = (vfloat4)(0.f);
    #pragma unroll 8
    for (int tt = 0; tt < TPB; ++tt) {
        const float a   = als[g * TPB + tt];
        const vfloat4 v = pr[tt * 256];
        acc.x = fmaf(a, v.x, acc.x);
        acc.y = fmaf(a, v.y, acc.y);
        acc.z = fmaf(a, v.z, acc.z);
        acc.w = fmaf(a, v.w, acc.w);
    }
    ((vfloat4*)ctp)[((size_t)b * NG + g) * 256 + tid] = acc;
}

// -------------------------------------------------------------------------
// K5: out_ct[b,e] = sum_g ctp[b,g,e]. grid = 64 blocks, 256 thr (f4 each).
// -------------------------------------------------------------------------
__global__ __launch_bounds__(256) void k_ctcomb(const float* __restrict__ ctp,
                                                float* __restrict__ out_ct) {
    const int tid = threadIdx.x;
    const int b   = blockIdx.x;
    const vfloat4* __restrict__ cp = (const vfloat4*)ctp + (size_t)b * NG * 256 + tid;
    vfloat4 acc = (vfloat4)(0.f);
    #pragma unroll
    for (int gg = 0; gg < NG; ++gg) {
        const vfloat4 v = cp[gg * 256];
        acc.x += v.x; acc.y += v.y; acc.z += v.z; acc.w += v.w;
    }
    ((vfloat4*)out_ct)[b * 256 + tid] = acc;
}

extern "C" void kernel_launch(void* const* d_in, const int* in_sizes, int n_in,
                              void* d_out, int out_size, void* d_ws, size_t ws_size,
                              hipStream_t stream) {
    const float* h    = (const float*)d_in[0];   // (64, 1024)
    const float* prev = (const float*)d_in[1];   // (64, 512, 1024)
    const float* W    = (const float*)d_in[2];   // (1, 1024, 1024)
    float* out    = (float*)d_out;
    float* out_ct = out;                         // (64, 1024)
    float* out_np = out + BB * TWOH;             // (64, 513, 1024)

    // ws layout (floats): q[64*1024] | s[64*512] | ctp[64*8*1024]  (~2.9 MB)
    float* q   = (float*)d_ws;
    float* sc  = q + BB * TWOH;
    float* ctp = sc + BB * TT;

    k_qgemm <<<dim3(4, BB),   256, 0, stream>>>(h, W, q);
    k_copy  <<<dim3(8192 + 64), 256, 0, stream>>>(prev, h, out_np);
    k_scores<<<dim3(128, BB), 256, 0, stream>>>(prev, q, sc);
    k_ct    <<<dim3(NG, BB),  256, 0, stream>>>(prev, sc, ctp);
    k_ctcomb<<<dim3(BB),      256, 0, stream>>>(ctp, out_ct);
}